// Round 19
// baseline (136.785 us; speedup 1.0000x reference)
//
#include <hip/hip_runtime.h>
#include <hip/hip_bf16.h>

#define NROWS 32768
#define KCODES 8192
#define DDIM 128
#define TT 2048
#define ETOT 4194304  // 16*128*2048

typedef __attribute__((ext_vector_type(8))) _Float16 f16x8;
typedef __attribute__((ext_vector_type(4))) float f32x4;

// pack: (v & ~0x1FFF) | p, p in [0,8191] -> single v_and_or_b32.
__device__ __forceinline__ float pk(float v, int p) {
    return __int_as_float((__float_as_int(v) & 0xFFFFE000) | p);
}

__device__ __forceinline__ void async16(char* lds_uniform, const char* g_perlane) {
    __builtin_amdgcn_global_load_lds(
        (const __attribute__((address_space(1))) unsigned int*)g_perlane,
        (__attribute__((address_space(3))) unsigned int*)lds_uniform,
        16, 0, 0);
}

#define SYNC2 asm volatile("s_waitcnt vmcnt(2) lgkmcnt(0)\n\ts_barrier" ::: "memory")
#define SYNC0 asm volatile("s_waitcnt vmcnt(0) lgkmcnt(0)\n\ts_barrier" ::: "memory")

// ---------------------------------------------------------------------------
// k_prep (merged): blocks [0,2048) = codebook normalize fp32->fp16 into MFMA
// A-fragment order (16-code tiles, 4KB); blocks [2048,3072) = transpose
// inputs [B,D,T] -> xh [N,D] fp16.
// ---------------------------------------------------------------------------
__global__ void k_prep(const float* __restrict__ cb, _Float16* __restrict__ eh,
                       const float* __restrict__ in, _Float16* __restrict__ xh) {
    __shared__ float tb[64][65];
    int bid = blockIdx.x;
    if (bid < 2048) {
        int w = (bid * blockDim.x + threadIdx.x) >> 6;  // code id
        int l = threadIdx.x & 63;
        if (w >= KCODES) return;
        const float* row = cb + (long)w * DDIM;
        float v0 = row[l], v1 = row[l + 64];
        float ss = v0 * v0 + v1 * v1;
#pragma unroll
        for (int s = 1; s < 64; s <<= 1) ss += __shfl_xor(ss, s, 64);
        float inv = 1.0f / fmaxf(sqrtf(ss), 1e-12f);
        int tile = w >> 4, c = w & 15;
#pragma unroll
        for (int e = 0; e < 2; e++) {
            int d = l + e * 64;
            float v = (e ? v1 : v0) * inv;
            int ks = d >> 5, kq = (d >> 3) & 3, dr = d & 7;
            long off = (long)tile * 2048 + ks * 512 + (kq * 16 + c) * 8 + dr;
            eh[off] = (_Float16)v;
        }
    } else {
        bid -= 2048;
        int tt0 = (bid & 31) * 64;
        int dd0 = ((bid >> 5) & 1) * 64;
        int b = bid >> 6;
        const float* base = in + (long)b * DDIM * TT;
        int tl = threadIdx.x & 63;
        int dg = threadIdx.x >> 6;
#pragma unroll
        for (int i = 0; i < 16; i++) {
            int dd = dg + i * 4;
            tb[dd][tl] = base[(long)(dd0 + dd) * TT + tt0 + tl];
        }
        __syncthreads();
        int dl = threadIdx.x & 63;
        int tg = threadIdx.x >> 6;
#pragma unroll
        for (int i = 0; i < 16; i++) {
            int t = tg + i * 4;
            long n = (long)b * TT + tt0 + t;
            xh[n * DDIM + dd0 + dl] = (_Float16)tb[dl][t];
        }
    }
}

// ---------------------------------------------------------------------------
// mfma4i: ks-outer (4 independent chains interleaved by construction).
// ---------------------------------------------------------------------------
__device__ __forceinline__ void mfma4i(const char* buf, int l,
                                       const f16x8 (&bx)[4][4], f32x4 (&acc)[4]) {
    const f32x4 Z = {0.f, 0.f, 0.f, 0.f};
    f16x8 ah[4];
#pragma unroll
    for (int ks = 0; ks < 4; ks++)
        ah[ks] = *(const f16x8*)(buf + ks * 1024 + l * 16);
    __builtin_amdgcn_s_setprio(1);
#pragma unroll
    for (int nf = 0; nf < 4; nf++)
        acc[nf] = __builtin_amdgcn_mfma_f32_16x16x32_f16(ah[0], bx[nf][0], Z, 0, 0, 0);
#pragma unroll
    for (int ks = 1; ks < 4; ks++)
#pragma unroll
        for (int nf = 0; nf < 4; nf++)
            acc[nf] = __builtin_amdgcn_mfma_f32_16x16x32_f16(ah[ks], bx[nf][ks], acc[nf], 0, 0, 0);
    __builtin_amdgcn_s_setprio(0);
}

// {t1,t2,u1}: exact top-2 per eighth (cross-quad via t1/t2, same-quad 2nd
// via u1); feeds the 16-candidate exact fp64 refine.
__device__ __forceinline__ void sel4(const f32x4 (&acc)[4], int PP,
                                     float (&t1)[4], float (&t2)[4], float (&u1)[4]) {
#pragma unroll
    for (int nf = 0; nf < 4; nf++) {
        f32x4 a = acc[nf];
        float s0 = pk(a[0], PP),     s1 = pk(a[1], PP - 1);
        float s2 = pk(a[2], PP - 2), s3 = pk(a[3], PP - 3);
        float h01 = fmaxf(s0, s1), l01 = fminf(s0, s1);
        float h23 = fmaxf(s2, s3), l23 = fminf(s2, s3);
        float m1 = fmaxf(h01, h23);                          // quad max
        float m2 = fmaxf(fminf(h01, h23), fmaxf(l01, l23));  // quad 2nd
        float n1 = fminf(t1[nf], m1); t1[nf] = fmaxf(t1[nf], m1);
        t2[nf] = fmaxf(t2[nf], n1);
        u1[nf] = fmaxf(u1[nf], m2);
    }
}

// ---------------------------------------------------------------------------
// k3 v18: SINGLE-acc + 2-tile phases + 4 waves/SIMD (the untested cell of
// the {acc-pipeline x occupancy} matrix; dual-acc at 4w/SIMD spills, r14).
// Register fit: bx 64 + acc 16 + ah 16 + trackers 12 + addr ~15 = ~123 <=
// 128. Compact dynamic rotation (r17's static unroll blew L1i).
// ---------------------------------------------------------------------------
__global__ __launch_bounds__(256, 4) void k_main(const _Float16* __restrict__ xh,
                                                 const _Float16* __restrict__ eh,
                                                 int* __restrict__ cand) {
    extern __shared__ char lds[];
    const int tid = threadIdx.x;
    const int l = tid & 63;
    const int w = tid >> 6;
    const int e8 = blockIdx.x & 7;
    const int rb = blockIdx.x >> 3;
    const int col = l & 15, kq = l >> 4;
    const long rbase = (long)rb * 256;

    f16x8 bx[4][4];
#pragma unroll
    for (int nf = 0; nf < 4; nf++) {
        long n = rbase + w * 64 + nf * 16 + col;
#pragma unroll
        for (int ks = 0; ks < 4; ks++)
            bx[nf][ks] = *(const f16x8*)(xh + n * DDIM + ks * 32 + kq * 8);
    }

    const float NEG = __int_as_float(0xFF800000);
    float t1[4], t2[4], u1[4];
#pragma unroll
    for (int i = 0; i < 4; i++) { t1[i] = t2[i] = u1[i] = NEG; }

    int P = 8191 - (e8 * 1024 + kq * 4);

    const char* gsrc = (const char*)eh + (long)e8 * 262144 + w * 1024 + l * 16;
    char* b0 = lds;
    char* b1 = lds + 8192;
    char* b2 = lds + 16384;

    // prologue: stage phases 0,1 (2 tiles = 2 async16 each)
    async16(b0 + w * 1024, gsrc);
    async16(b0 + 4096 + w * 1024, gsrc + 4096);
    async16(b1 + w * 1024, gsrc + 8192);
    async16(b1 + 4096 + w * 1024, gsrc + 12288);

    f32x4 acc[4];

    for (int p = 0; p < 32; ++p) {
        if (p < 30) {
            SYNC2;
            async16(b2 + w * 1024, gsrc + (long)(p + 2) * 8192);
            async16(b2 + 4096 + w * 1024, gsrc + (long)(p + 2) * 8192 + 4096);
        } else if (p == 30) {
            SYNC2;
        } else {
            SYNC0;
        }
        mfma4i(b0, l, bx, acc);
        sel4(acc, P, t1, t2, u1); P -= 16;
        mfma4i(b0 + 4096, l, bx, acc);
        sel4(acc, P, t1, t2, u1); P -= 16;
        char* tp = b0; b0 = b1; b1 = b2; b2 = tp;
    }

    __syncthreads();  // all staging/reads done; reuse LDS base for merge
    float* mrg = (float*)lds;  // [256 rows][13]
#pragma unroll
    for (int nf = 0; nf < 4; nf++) {
        int row = w * 64 + nf * 16 + col;
        int e = kq * 3;
        mrg[row * 13 + e + 0] = t1[nf];
        mrg[row * 13 + e + 1] = t2[nf];
        mrg[row * 13 + e + 2] = u1[nf];
    }
    __syncthreads();
    {
        float s1 = NEG, s2 = NEG;
#pragma unroll 4
        for (int e = 0; e < 12; e++) {
            float v = mrg[tid * 13 + e];
            float a1 = fminf(s1, v); s1 = fmaxf(s1, v);
            s2 = fmaxf(s2, a1);
        }
        long n = rbase + tid;
        int* cp = cand + n * 16 + e8 * 2;
        cp[0] = 8191 - (__float_as_int(s1) & 0x1FFF);
        cp[1] = 8191 - (__float_as_int(s2) & 0x1FFF);
    }
}

// ---------------------------------------------------------------------------
// k4 v6 (FUSED refine + out + loss): block = 16 rows; x-slab staged in LDS
// once; 16 lanes/row score 16 candidates in fp64 (xs read as float4 --
// 528B row stride is 16B-aligned); winner -> idx + out + loss partials.
// ---------------------------------------------------------------------------
__global__ void k_rf(const float* __restrict__ in, const float* __restrict__ cb,
                     const int* __restrict__ cand, float* __restrict__ out,
                     float* __restrict__ idx_f, double* __restrict__ part) {
    __shared__ float xs[16][132];   // [t-local][d], pad 4 (row = 528B, 16B-aligned)
    __shared__ int sbi[16];
    __shared__ double sd[256];
    const int tid = threadIdx.x;
    const int n0 = blockIdx.x * 16;
    const int b = n0 >> 11, t0 = n0 & 2047;

    {
        int d = tid >> 1, h = tid & 1;
        const float* src = in + ((long)b * DDIM + d) * TT + t0 + h * 8;
        float4 v0 = *(const float4*)src;
        float4 v1 = *(const float4*)(src + 4);
#pragma unroll
        for (int j = 0; j < 4; j++) {
            xs[h * 8 + j][d] = ((const float*)&v0)[j];
            xs[h * 8 + 4 + j][d] = ((const float*)&v1)[j];
        }
    }
    __syncthreads();

    {
        int r = tid >> 4, k = tid & 15;
        int n = n0 + r;
        int c = cand[n * 16 + k];
        const float4* e = (const float4*)(cb + (long)c * DDIM);
        const float4* xr = (const float4*)&xs[r][0];
        double dot = 0.0, nrm = 0.0;
        for (int d4 = 0; d4 < 32; d4++) {
            float4 q = e[d4];
            float4 xv = xr[d4];
#pragma unroll
            for (int j = 0; j < 4; j++) {
                double xd = (double)((const float*)&xv)[j];
                double f = (double)((const float*)&q)[j];
                dot += xd * f;
                nrm += f * f;
            }
        }
        double sv = dot / fmax(sqrt(nrm), 1e-12);
#pragma unroll
        for (int s = 1; s < 16; s <<= 1) {
            double osv = __shfl_xor(sv, s, 64);
            int oc = __shfl_xor(c, s, 64);
            if (osv > sv || (osv == sv && oc < c)) { sv = osv; c = oc; }
        }
        if (k == 0) {
            sbi[r] = c;
            idx_f[n] = (float)c;
        }
    }
    __syncthreads();

    {
        int d = tid >> 1, h = tid & 1;
        float* ob = out + ((long)b * DDIM + d) * TT + t0 + h * 8;
        double acc = 0.0;
        float ov[8];
#pragma unroll
        for (int j = 0; j < 8; j++) {
            int rr = h * 8 + j;
            float xv = xs[rr][d];
            float qv = cb[(long)sbi[rr] * DDIM + d];
            float diff = qv - xv;
            ov[j] = xv + diff;
            acc += (double)diff * (double)diff;
        }
        *(float4*)ob = make_float4(ov[0], ov[1], ov[2], ov[3]);
        *(float4*)(ob + 4) = make_float4(ov[4], ov[5], ov[6], ov[7]);
        sd[tid] = acc;
    }
    __syncthreads();
    for (int s = 128; s > 0; s >>= 1) {
        if (tid < s) sd[tid] += sd[tid + s];
        __syncthreads();
    }
    if (tid == 0) part[blockIdx.x] = sd[0];
}

__global__ void k_loss_final(const double* __restrict__ part, int np,
                             float* __restrict__ loss) {
    __shared__ double sd[256];
    double a = 0.0;
    for (int i = threadIdx.x; i < np; i += 256) a += part[i];
    sd[threadIdx.x] = a;
    __syncthreads();
    for (int s = 128; s > 0; s >>= 1) {
        if (threadIdx.x < s) sd[threadIdx.x] += sd[threadIdx.x + s];
        __syncthreads();
    }
    if (threadIdx.x == 0) {
        float m = (float)(sd[0] / (double)ETOT);
        loss[0] = m + 0.02f * m;
    }
}

// ---------------------------------------------------------------------------
extern "C" void kernel_launch(void* const* d_in, const int* in_sizes, int n_in,
                              void* d_out, int out_size, void* d_ws, size_t ws_size,
                              hipStream_t stream) {
    const float* inputs = (const float*)d_in[0];   // [16,128,2048] fp32
    const float* cb     = (const float*)d_in[1];   // [8192,128]    fp32
    float* outf = (float*)d_out;                   // [loss | out(B,D,T) | idx]

    char* ws = (char*)d_ws;
    _Float16* xh = (_Float16*)ws; ws += (long)NROWS * DDIM * 2;
    _Float16* eh = (_Float16*)ws; ws += (long)KCODES * DDIM * 2;
    int* cand    = (int*)ws;      ws += (long)NROWS * 16 * 4;
    double* part = (double*)ws;   ws += 2048 * 8;

    k_prep<<<dim3(3072), dim3(256), 0, stream>>>(cb, eh, inputs, xh);
    k_main<<<dim3(1024), dim3(256), 24576, stream>>>(xh, eh, cand);
    k_rf<<<dim3(2048), dim3(256), 0, stream>>>(inputs, cb, cand, outf + 1,
                                               outf + 1 + (long)ETOT, part);
    k_loss_final<<<dim3(1), dim3(256), 0, stream>>>(part, 2048, outf);
}

// Round 20
// 132.847 us; speedup vs baseline: 1.0296x; 1.0296x over previous
//
#include <hip/hip_runtime.h>
#include <hip/hip_bf16.h>

#define NROWS 32768
#define KCODES 8192
#define DDIM 128
#define TT 2048
#define ETOT 4194304  // 16*128*2048

typedef __attribute__((ext_vector_type(8))) _Float16 f16x8;
typedef __attribute__((ext_vector_type(4))) float f32x4;

// pack: (v & ~0x1FFF) | p, p in [0,8191] -> single v_and_or_b32.
__device__ __forceinline__ float pk(float v, int p) {
    return __int_as_float((__float_as_int(v) & 0xFFFFE000) | p);
}

__device__ __forceinline__ void async16(char* lds_uniform, const char* g_perlane) {
    __builtin_amdgcn_global_load_lds(
        (const __attribute__((address_space(1))) unsigned int*)g_perlane,
        (__attribute__((address_space(3))) unsigned int*)lds_uniform,
        16, 0, 0);
}

#define SYNC2 asm volatile("s_waitcnt vmcnt(2) lgkmcnt(0)\n\ts_barrier" ::: "memory")
#define SYNC0 asm volatile("s_waitcnt vmcnt(0) lgkmcnt(0)\n\ts_barrier" ::: "memory")

// ---------------------------------------------------------------------------
// k_prep (merged): blocks [0,2048) = codebook normalize fp32->fp16 into MFMA
// A-fragment order (16-code tiles, 4KB); blocks [2048,3072) = transpose
// inputs [B,D,T] -> xh [N,D] fp16.
// ---------------------------------------------------------------------------
__global__ void k_prep(const float* __restrict__ cb, _Float16* __restrict__ eh,
                       const float* __restrict__ in, _Float16* __restrict__ xh) {
    __shared__ float tb[64][65];
    int bid = blockIdx.x;
    if (bid < 2048) {
        int w = (bid * blockDim.x + threadIdx.x) >> 6;  // code id
        int l = threadIdx.x & 63;
        if (w >= KCODES) return;
        const float* row = cb + (long)w * DDIM;
        float v0 = row[l], v1 = row[l + 64];
        float ss = v0 * v0 + v1 * v1;
#pragma unroll
        for (int s = 1; s < 64; s <<= 1) ss += __shfl_xor(ss, s, 64);
        float inv = 1.0f / fmaxf(sqrtf(ss), 1e-12f);
        int tile = w >> 4, c = w & 15;
#pragma unroll
        for (int e = 0; e < 2; e++) {
            int d = l + e * 64;
            float v = (e ? v1 : v0) * inv;
            int ks = d >> 5, kq = (d >> 3) & 3, dr = d & 7;
            long off = (long)tile * 2048 + ks * 512 + (kq * 16 + c) * 8 + dr;
            eh[off] = (_Float16)v;
        }
    } else {
        bid -= 2048;
        int tt0 = (bid & 31) * 64;
        int dd0 = ((bid >> 5) & 1) * 64;
        int b = bid >> 6;
        const float* base = in + (long)b * DDIM * TT;
        int tl = threadIdx.x & 63;
        int dg = threadIdx.x >> 6;
#pragma unroll
        for (int i = 0; i < 16; i++) {
            int dd = dg + i * 4;
            tb[dd][tl] = base[(long)(dd0 + dd) * TT + tt0 + tl];
        }
        __syncthreads();
        int dl = threadIdx.x & 63;
        int tg = threadIdx.x >> 6;
#pragma unroll
        for (int i = 0; i < 16; i++) {
            int t = tg + i * 4;
            long n = (long)b * TT + tt0 + t;
            xh[n * DDIM + dd0 + dl] = (_Float16)tb[dl][t];
        }
    }
}

// ---------------------------------------------------------------------------
// mfma4i: ks-outer (4 independent chains interleaved by construction).
// NO setprio -- r20 ablation: prio1-MFMA vs prio0-sel can block-convoy
// through s_barrier (starved sel wave delays its block's 3 siblings).
// ---------------------------------------------------------------------------
__device__ __forceinline__ void mfma4i(const char* buf, int l,
                                       const f16x8 (&bx)[4][4], f32x4 (&acc)[4]) {
    const f32x4 Z = {0.f, 0.f, 0.f, 0.f};
    f16x8 ah[4];
#pragma unroll
    for (int ks = 0; ks < 4; ks++)
        ah[ks] = *(const f16x8*)(buf + ks * 1024 + l * 16);
#pragma unroll
    for (int nf = 0; nf < 4; nf++)
        acc[nf] = __builtin_amdgcn_mfma_f32_16x16x32_f16(ah[0], bx[nf][0], Z, 0, 0, 0);
#pragma unroll
    for (int ks = 1; ks < 4; ks++)
#pragma unroll
        for (int nf = 0; nf < 4; nf++)
            acc[nf] = __builtin_amdgcn_mfma_f32_16x16x32_f16(ah[ks], bx[nf][ks], acc[nf], 0, 0, 0);
}

// {t1,t2,u1}: exact top-2 per eighth (cross-quad via t1/t2, same-quad 2nd
// via u1); feeds the 16-candidate exact fp64 refine.
__device__ __forceinline__ void sel4(const f32x4 (&acc)[4], int PP,
                                     float (&t1)[4], float (&t2)[4], float (&u1)[4]) {
#pragma unroll
    for (int nf = 0; nf < 4; nf++) {
        f32x4 a = acc[nf];
        float s0 = pk(a[0], PP),     s1 = pk(a[1], PP - 1);
        float s2 = pk(a[2], PP - 2), s3 = pk(a[3], PP - 3);
        float h01 = fmaxf(s0, s1), l01 = fminf(s0, s1);
        float h23 = fmaxf(s2, s3), l23 = fminf(s2, s3);
        float m1 = fmaxf(h01, h23);                          // quad max
        float m2 = fmaxf(fminf(h01, h23), fmaxf(l01, l23));  // quad 2nd
        float n1 = fminf(t1[nf], m1); t1[nf] = fmaxf(t1[nf], m1);
        t2[nf] = fmaxf(t2[nf], n1);
        u1[nf] = fmaxf(u1[nf], m2);
    }
}

// ---------------------------------------------------------------------------
// k3 v19: byte-identical to r16/r18's dual-acc sel-shadow pipeline EXCEPT
// setprio removed (never ablated since r8; m190: setprio hurts barrier-
// synced GEMM). 2-tile phases, 3 x 8KB buffers, counted vmcnt(2).
// ---------------------------------------------------------------------------
__global__ __launch_bounds__(256, 3) void k_main(const _Float16* __restrict__ xh,
                                                 const _Float16* __restrict__ eh,
                                                 int* __restrict__ cand) {
    extern __shared__ char lds[];
    const int tid = threadIdx.x;
    const int l = tid & 63;
    const int w = tid >> 6;
    const int e8 = blockIdx.x & 7;
    const int rb = blockIdx.x >> 3;
    const int col = l & 15, kq = l >> 4;
    const long rbase = (long)rb * 256;

    f16x8 bx[4][4];
#pragma unroll
    for (int nf = 0; nf < 4; nf++) {
        long n = rbase + w * 64 + nf * 16 + col;
#pragma unroll
        for (int ks = 0; ks < 4; ks++)
            bx[nf][ks] = *(const f16x8*)(xh + n * DDIM + ks * 32 + kq * 8);
    }

    const float NEG = __int_as_float(0xFF800000);
    float t1[4], t2[4], u1[4];
#pragma unroll
    for (int i = 0; i < 4; i++) { t1[i] = t2[i] = u1[i] = NEG; }

    int P = 8191 - (e8 * 1024 + kq * 4);

    const char* gsrc = (const char*)eh + (long)e8 * 262144 + w * 1024 + l * 16;
    char* b0 = lds;
    char* b1 = lds + 8192;
    char* b2 = lds + 16384;

    // prologue: stage phases 0,1 (2 tiles = 2 async16 each)
    async16(b0 + w * 1024, gsrc);
    async16(b0 + 4096 + w * 1024, gsrc + 4096);
    async16(b1 + w * 1024, gsrc + 8192);
    async16(b1 + 4096 + w * 1024, gsrc + 12288);

    f32x4 accA[4], accB[4];
    int PA, PB;

    // phase 0 (peeled: no prev accB)
    SYNC2;
    async16(b2 + w * 1024, gsrc + 2 * 8192);
    async16(b2 + 4096 + w * 1024, gsrc + 2 * 8192 + 4096);
    mfma4i(b0, l, bx, accA); PA = P; P -= 16;
    mfma4i(b0 + 4096, l, bx, accB); PB = P; P -= 16;
    sel4(accA, PA, t1, t2, u1);
    { char* tp = b0; b0 = b1; b1 = b2; b2 = tp; }

    for (int p = 1; p <= 30; ++p) {
        SYNC2;
        if (p < 30) {
            async16(b2 + w * 1024, gsrc + (long)(p + 2) * 8192);
            async16(b2 + 4096 + w * 1024, gsrc + (long)(p + 2) * 8192 + 4096);
        }
        mfma4i(b0, l, bx, accA); PA = P; P -= 16;
        sel4(accB, PB, t1, t2, u1);          // prev phase's tile 1
        mfma4i(b0 + 4096, l, bx, accB); PB = P; P -= 16;
        sel4(accA, PA, t1, t2, u1);
        { char* tp = b0; b0 = b1; b1 = b2; b2 = tp; }
    }
    // phase 31 (peeled: final drain)
    SYNC0;
    mfma4i(b0, l, bx, accA); PA = P; P -= 16;
    sel4(accB, PB, t1, t2, u1);
    mfma4i(b0 + 4096, l, bx, accB); PB = P;
    sel4(accA, PA, t1, t2, u1);
    sel4(accB, PB, t1, t2, u1);

    __syncthreads();  // all staging/reads done; reuse LDS base for merge
    float* mrg = (float*)lds;  // [256 rows][13]
#pragma unroll
    for (int nf = 0; nf < 4; nf++) {
        int row = w * 64 + nf * 16 + col;
        int e = kq * 3;
        mrg[row * 13 + e + 0] = t1[nf];
        mrg[row * 13 + e + 1] = t2[nf];
        mrg[row * 13 + e + 2] = u1[nf];
    }
    __syncthreads();
    {
        float s1 = NEG, s2 = NEG;
#pragma unroll 4
        for (int e = 0; e < 12; e++) {
            float v = mrg[tid * 13 + e];
            float a1 = fminf(s1, v); s1 = fmaxf(s1, v);
            s2 = fmaxf(s2, a1);
        }
        long n = rbase + tid;
        int* cp = cand + n * 16 + e8 * 2;
        cp[0] = 8191 - (__float_as_int(s1) & 0x1FFF);
        cp[1] = 8191 - (__float_as_int(s2) & 0x1FFF);
    }
}

// ---------------------------------------------------------------------------
// k4 v5 (FUSED refine + out + loss): block = 16 rows; x-slab staged in LDS
// once; 16 lanes/row score 16 candidates in fp64; winner -> idx + out +
// fp64 loss partials. (r16/r18 proven form.)
// ---------------------------------------------------------------------------
__global__ void k_rf(const float* __restrict__ in, const float* __restrict__ cb,
                     const int* __restrict__ cand, float* __restrict__ out,
                     float* __restrict__ idx_f, double* __restrict__ part) {
    __shared__ float xs[16][132];   // [t-local][d], pad 4
    __shared__ int sbi[16];
    __shared__ double sd[256];
    const int tid = threadIdx.x;
    const int n0 = blockIdx.x * 16;
    const int b = n0 >> 11, t0 = n0 & 2047;

    {
        int d = tid >> 1, h = tid & 1;
        const float* src = in + ((long)b * DDIM + d) * TT + t0 + h * 8;
        float4 v0 = *(const float4*)src;
        float4 v1 = *(const float4*)(src + 4);
#pragma unroll
        for (int j = 0; j < 4; j++) {
            xs[h * 8 + j][d] = ((const float*)&v0)[j];
            xs[h * 8 + 4 + j][d] = ((const float*)&v1)[j];
        }
    }
    __syncthreads();

    {
        int r = tid >> 4, k = tid & 15;
        int n = n0 + r;
        int c = cand[n * 16 + k];
        const float4* e = (const float4*)(cb + (long)c * DDIM);
        double dot = 0.0, nrm = 0.0;
        for (int d4 = 0; d4 < 32; d4++) {
            float4 q = e[d4];
#pragma unroll
            for (int j = 0; j < 4; j++) {
                double xd = (double)xs[r][d4 * 4 + j];
                double f = (double)((const float*)&q)[j];
                dot += xd * f;
                nrm += f * f;
            }
        }
        double sv = dot / fmax(sqrt(nrm), 1e-12);
#pragma unroll
        for (int s = 1; s < 16; s <<= 1) {
            double osv = __shfl_xor(sv, s, 64);
            int oc = __shfl_xor(c, s, 64);
            if (osv > sv || (osv == sv && oc < c)) { sv = osv; c = oc; }
        }
        if (k == 0) {
            sbi[r] = c;
            idx_f[n] = (float)c;
        }
    }
    __syncthreads();

    {
        int d = tid >> 1, h = tid & 1;
        float* ob = out + ((long)b * DDIM + d) * TT + t0 + h * 8;
        double acc = 0.0;
        float ov[8];
#pragma unroll
        for (int j = 0; j < 8; j++) {
            int rr = h * 8 + j;
            float xv = xs[rr][d];
            float qv = cb[(long)sbi[rr] * DDIM + d];
            float diff = qv - xv;
            ov[j] = xv + diff;
            acc += (double)diff * (double)diff;
        }
        *(float4*)ob = make_float4(ov[0], ov[1], ov[2], ov[3]);
        *(float4*)(ob + 4) = make_float4(ov[4], ov[5], ov[6], ov[7]);
        sd[tid] = acc;
    }
    __syncthreads();
    for (int s = 128; s > 0; s >>= 1) {
        if (tid < s) sd[tid] += sd[tid + s];
        __syncthreads();
    }
    if (tid == 0) part[blockIdx.x] = sd[0];
}

__global__ void k_loss_final(const double* __restrict__ part, int np,
                             float* __restrict__ loss) {
    __shared__ double sd[256];
    double a = 0.0;
    for (int i = threadIdx.x; i < np; i += 256) a += part[i];
    sd[threadIdx.x] = a;
    __syncthreads();
    for (int s = 128; s > 0; s >>= 1) {
        if (threadIdx.x < s) sd[threadIdx.x] += sd[threadIdx.x + s];
        __syncthreads();
    }
    if (threadIdx.x == 0) {
        float m = (float)(sd[0] / (double)ETOT);
        loss[0] = m + 0.02f * m;
    }
}

// ---------------------------------------------------------------------------
extern "C" void kernel_launch(void* const* d_in, const int* in_sizes, int n_in,
                              void* d_out, int out_size, void* d_ws, size_t ws_size,
                              hipStream_t stream) {
    const float* inputs = (const float*)d_in[0];   // [16,128,2048] fp32
    const float* cb     = (const float*)d_in[1];   // [8192,128]    fp32
    float* outf = (float*)d_out;                   // [loss | out(B,D,T) | idx]

    char* ws = (char*)d_ws;
    _Float16* xh = (_Float16*)ws; ws += (long)NROWS * DDIM * 2;
    _Float16* eh = (_Float16*)ws; ws += (long)KCODES * DDIM * 2;
    int* cand    = (int*)ws;      ws += (long)NROWS * 16 * 4;
    double* part = (double*)ws;   ws += 2048 * 8;

    k_prep<<<dim3(3072), dim3(256), 0, stream>>>(cb, eh, inputs, xh);
    k_main<<<dim3(1024), dim3(256), 24576, stream>>>(xh, eh, cand);
    k_rf<<<dim3(2048), dim3(256), 0, stream>>>(inputs, cb, cand, outf + 1,
                                               outf + 1 + (long)ETOT, part);
    k_loss_final<<<dim3(1), dim3(256), 0, stream>>>(part, 2048, outf);
}

// Round 21
// 113.056 us; speedup vs baseline: 1.2099x; 1.1751x over previous
//
#include <hip/hip_runtime.h>
#include <hip/hip_bf16.h>

#define NROWS 32768
#define KCODES 8192
#define DDIM 128
#define TT 2048
#define ETOT 4194304  // 16*128*2048

typedef __attribute__((ext_vector_type(8))) _Float16 f16x8;
typedef __attribute__((ext_vector_type(4))) float f32x4;

// pack: (v & ~0x1FFF) | p, p in [0,8191] -> single v_and_or_b32.
__device__ __forceinline__ float pk(float v, int p) {
    return __int_as_float((__float_as_int(v) & 0xFFFFE000) | p);
}

__device__ __forceinline__ void async16(char* lds_uniform, const char* g_perlane) {
    __builtin_amdgcn_global_load_lds(
        (const __attribute__((address_space(1))) unsigned int*)g_perlane,
        (__attribute__((address_space(3))) unsigned int*)lds_uniform,
        16, 0, 0);
}

#define SYNC2 asm volatile("s_waitcnt vmcnt(2) lgkmcnt(0)\n\ts_barrier" ::: "memory")
#define SYNC0 asm volatile("s_waitcnt vmcnt(0) lgkmcnt(0)\n\ts_barrier" ::: "memory")

// ---------------------------------------------------------------------------
// k_prep (merged): blocks [0,2048) = codebook normalize fp32->fp16 into MFMA
// A-fragment order (16-code tiles, 4KB); blocks [2048,3072) = transpose
// inputs [B,D,T] -> xh [N,D] fp16.
// ---------------------------------------------------------------------------
__global__ void k_prep(const float* __restrict__ cb, _Float16* __restrict__ eh,
                       const float* __restrict__ in, _Float16* __restrict__ xh) {
    __shared__ float tb[64][65];
    int bid = blockIdx.x;
    if (bid < 2048) {
        int w = (bid * blockDim.x + threadIdx.x) >> 6;  // code id
        int l = threadIdx.x & 63;
        if (w >= KCODES) return;
        const float* row = cb + (long)w * DDIM;
        float v0 = row[l], v1 = row[l + 64];
        float ss = v0 * v0 + v1 * v1;
#pragma unroll
        for (int s = 1; s < 64; s <<= 1) ss += __shfl_xor(ss, s, 64);
        float inv = 1.0f / fmaxf(sqrtf(ss), 1e-12f);
        int tile = w >> 4, c = w & 15;
#pragma unroll
        for (int e = 0; e < 2; e++) {
            int d = l + e * 64;
            float v = (e ? v1 : v0) * inv;
            int ks = d >> 5, kq = (d >> 3) & 3, dr = d & 7;
            long off = (long)tile * 2048 + ks * 512 + (kq * 16 + c) * 8 + dr;
            eh[off] = (_Float16)v;
        }
    } else {
        bid -= 2048;
        int tt0 = (bid & 31) * 64;
        int dd0 = ((bid >> 5) & 1) * 64;
        int b = bid >> 6;
        const float* base = in + (long)b * DDIM * TT;
        int tl = threadIdx.x & 63;
        int dg = threadIdx.x >> 6;
#pragma unroll
        for (int i = 0; i < 16; i++) {
            int dd = dg + i * 4;
            tb[dd][tl] = base[(long)(dd0 + dd) * TT + tt0 + tl];
        }
        __syncthreads();
        int dl = threadIdx.x & 63;
        int tg = threadIdx.x >> 6;
#pragma unroll
        for (int i = 0; i < 16; i++) {
            int t = tg + i * 4;
            long n = (long)b * TT + tt0 + t;
            xh[n * DDIM + dd0 + dl] = (_Float16)tb[dl][t];
        }
    }
}

// ---------------------------------------------------------------------------
// mfma4i: ks-outer (4 independent chains interleaved by construction).
// No setprio (r20: removal = -3.2us; priority inversion convoyed the block).
// ---------------------------------------------------------------------------
__device__ __forceinline__ void mfma4i(const char* buf, int l,
                                       const f16x8 (&bx)[4][4], f32x4 (&acc)[4]) {
    const f32x4 Z = {0.f, 0.f, 0.f, 0.f};
    f16x8 ah[4];
#pragma unroll
    for (int ks = 0; ks < 4; ks++)
        ah[ks] = *(const f16x8*)(buf + ks * 1024 + l * 16);
#pragma unroll
    for (int nf = 0; nf < 4; nf++)
        acc[nf] = __builtin_amdgcn_mfma_f32_16x16x32_f16(ah[0], bx[nf][0], Z, 0, 0, 0);
#pragma unroll
    for (int ks = 1; ks < 4; ks++)
#pragma unroll
        for (int nf = 0; nf < 4; nf++)
            acc[nf] = __builtin_amdgcn_mfma_f32_16x16x32_f16(ah[ks], bx[nf][ks], acc[nf], 0, 0, 0);
}

// {t1,t2,u1}: exact top-2 per eighth (cross-quad via t1/t2, same-quad 2nd
// via u1); feeds the rank-gated exact fp64 refine.
__device__ __forceinline__ void sel4(const f32x4 (&acc)[4], int PP,
                                     float (&t1)[4], float (&t2)[4], float (&u1)[4]) {
#pragma unroll
    for (int nf = 0; nf < 4; nf++) {
        f32x4 a = acc[nf];
        float s0 = pk(a[0], PP),     s1 = pk(a[1], PP - 1);
        float s2 = pk(a[2], PP - 2), s3 = pk(a[3], PP - 3);
        float h01 = fmaxf(s0, s1), l01 = fminf(s0, s1);
        float h23 = fmaxf(s2, s3), l23 = fminf(s2, s3);
        float m1 = fmaxf(h01, h23);                          // quad max
        float m2 = fmaxf(fminf(h01, h23), fmaxf(l01, l23));  // quad 2nd
        float n1 = fminf(t1[nf], m1); t1[nf] = fmaxf(t1[nf], m1);
        t2[nf] = fmaxf(t2[nf], n1);
        u1[nf] = fmaxf(u1[nf], m2);
    }
}

// ---------------------------------------------------------------------------
// k3 v20: r20's plateau kernel (dual-acc sel-shadow, 2-tile phases, 3x8KB,
// counted vmcnt(2), no setprio). Only change: epilogue stores PACKED score
// floats (value|payload bits) -- decode moved to k_rf.
// ---------------------------------------------------------------------------
__global__ __launch_bounds__(256, 3) void k_main(const _Float16* __restrict__ xh,
                                                 const _Float16* __restrict__ eh,
                                                 int* __restrict__ cand) {
    extern __shared__ char lds[];
    const int tid = threadIdx.x;
    const int l = tid & 63;
    const int w = tid >> 6;
    const int e8 = blockIdx.x & 7;
    const int rb = blockIdx.x >> 3;
    const int col = l & 15, kq = l >> 4;
    const long rbase = (long)rb * 256;

    f16x8 bx[4][4];
#pragma unroll
    for (int nf = 0; nf < 4; nf++) {
        long n = rbase + w * 64 + nf * 16 + col;
#pragma unroll
        for (int ks = 0; ks < 4; ks++)
            bx[nf][ks] = *(const f16x8*)(xh + n * DDIM + ks * 32 + kq * 8);
    }

    const float NEG = __int_as_float(0xFF800000);
    float t1[4], t2[4], u1[4];
#pragma unroll
    for (int i = 0; i < 4; i++) { t1[i] = t2[i] = u1[i] = NEG; }

    int P = 8191 - (e8 * 1024 + kq * 4);

    const char* gsrc = (const char*)eh + (long)e8 * 262144 + w * 1024 + l * 16;
    char* b0 = lds;
    char* b1 = lds + 8192;
    char* b2 = lds + 16384;

    // prologue: stage phases 0,1 (2 tiles = 2 async16 each)
    async16(b0 + w * 1024, gsrc);
    async16(b0 + 4096 + w * 1024, gsrc + 4096);
    async16(b1 + w * 1024, gsrc + 8192);
    async16(b1 + 4096 + w * 1024, gsrc + 12288);

    f32x4 accA[4], accB[4];
    int PA, PB;

    // phase 0 (peeled: no prev accB)
    SYNC2;
    async16(b2 + w * 1024, gsrc + 2 * 8192);
    async16(b2 + 4096 + w * 1024, gsrc + 2 * 8192 + 4096);
    mfma4i(b0, l, bx, accA); PA = P; P -= 16;
    mfma4i(b0 + 4096, l, bx, accB); PB = P; P -= 16;
    sel4(accA, PA, t1, t2, u1);
    { char* tp = b0; b0 = b1; b1 = b2; b2 = tp; }

    for (int p = 1; p <= 30; ++p) {
        SYNC2;
        if (p < 30) {
            async16(b2 + w * 1024, gsrc + (long)(p + 2) * 8192);
            async16(b2 + 4096 + w * 1024, gsrc + (long)(p + 2) * 8192 + 4096);
        }
        mfma4i(b0, l, bx, accA); PA = P; P -= 16;
        sel4(accB, PB, t1, t2, u1);          // prev phase's tile 1
        mfma4i(b0 + 4096, l, bx, accB); PB = P; P -= 16;
        sel4(accA, PA, t1, t2, u1);
        { char* tp = b0; b0 = b1; b1 = b2; b2 = tp; }
    }
    // phase 31 (peeled: final drain)
    SYNC0;
    mfma4i(b0, l, bx, accA); PA = P; P -= 16;
    sel4(accB, PB, t1, t2, u1);
    mfma4i(b0 + 4096, l, bx, accB); PB = P;
    sel4(accA, PA, t1, t2, u1);
    sel4(accB, PB, t1, t2, u1);

    __syncthreads();  // all staging/reads done; reuse LDS base for merge
    float* mrg = (float*)lds;  // [256 rows][13]
#pragma unroll
    for (int nf = 0; nf < 4; nf++) {
        int row = w * 64 + nf * 16 + col;
        int e = kq * 3;
        mrg[row * 13 + e + 0] = t1[nf];
        mrg[row * 13 + e + 1] = t2[nf];
        mrg[row * 13 + e + 2] = u1[nf];
    }
    __syncthreads();
    {
        float s1 = NEG, s2 = NEG;
#pragma unroll 4
        for (int e = 0; e < 12; e++) {
            float v = mrg[tid * 13 + e];
            float a1 = fminf(s1, v); s1 = fmaxf(s1, v);
            s2 = fmaxf(s2, a1);
        }
        long n = rbase + tid;
        int* cp = cand + n * 16 + e8 * 2;
        cp[0] = __float_as_int(s1);   // packed: trunc-value | (8191-code)
        cp[1] = __float_as_int(s2);
    }
}

// ---------------------------------------------------------------------------
// k4 v7 (rank-gated FUSED refine + out + loss): block = 16 rows; x-slab in
// LDS once; 16 lanes/row hold the 16 PACKED candidates, rank them via 16
// shuffles (all distinct: payload bits differ), and only the approx-TOP-4
// lanes run the fp64 scoring -- cb gather volume drops 4x (268->67 MB).
// Refine-top-4 semantics == rounds 5-11 (absmax=0 proven). Winner -> idx +
// out + fp64 loss partials.
// ---------------------------------------------------------------------------
__global__ void k_rf(const float* __restrict__ in, const float* __restrict__ cb,
                     const int* __restrict__ cand, float* __restrict__ out,
                     float* __restrict__ idx_f, double* __restrict__ part) {
    __shared__ float xs[16][132];   // [t-local][d], pad 4
    __shared__ int sbi[16];
    __shared__ double sd[256];
    const int tid = threadIdx.x;
    const int l = tid & 63;
    const int n0 = blockIdx.x * 16;
    const int b = n0 >> 11, t0 = n0 & 2047;

    {
        int d = tid >> 1, h = tid & 1;
        const float* src = in + ((long)b * DDIM + d) * TT + t0 + h * 8;
        float4 v0 = *(const float4*)src;
        float4 v1 = *(const float4*)(src + 4);
#pragma unroll
        for (int j = 0; j < 4; j++) {
            xs[h * 8 + j][d] = ((const float*)&v0)[j];
            xs[h * 8 + 4 + j][d] = ((const float*)&v1)[j];
        }
    }
    __syncthreads();

    {
        int r = tid >> 4, k = tid & 15;
        int n = n0 + r;
        float pkv = __int_as_float(cand[n * 16 + k]);

        // rank among this row's 16 lanes (packed values are distinct)
        int rank = 0;
        int gb = l & ~15;
#pragma unroll
        for (int j = 0; j < 16; j++) {
            float o = __shfl(pkv, gb | j, 64);
            rank += (o > pkv) ? 1 : 0;
        }

        double sv = -1e300;
        int c = 0x7fffffff;
        if (rank < 4) {   // approx top-4: exact fp64 re-evaluation
            c = 8191 - (__float_as_int(pkv) & 0x1FFF);
            const float4* e = (const float4*)(cb + (long)c * DDIM);
            double dot = 0.0, nrm = 0.0;
            for (int d4 = 0; d4 < 32; d4++) {
                float4 q = e[d4];
#pragma unroll
                for (int j = 0; j < 4; j++) {
                    double xd = (double)xs[r][d4 * 4 + j];
                    double f = (double)((const float*)&q)[j];
                    dot += xd * f;
                    nrm += f * f;
                }
            }
            sv = dot / fmax(sqrt(nrm), 1e-12);
        }
#pragma unroll
        for (int s = 1; s < 16; s <<= 1) {
            double osv = __shfl_xor(sv, s, 64);
            int oc = __shfl_xor(c, s, 64);
            if (osv > sv || (osv == sv && oc < c)) { sv = osv; c = oc; }
        }
        if (k == 0) {
            sbi[r] = c;
            idx_f[n] = (float)c;
        }
    }
    __syncthreads();

    {
        int d = tid >> 1, h = tid & 1;
        float* ob = out + ((long)b * DDIM + d) * TT + t0 + h * 8;
        double acc = 0.0;
        float ov[8];
#pragma unroll
        for (int j = 0; j < 8; j++) {
            int rr = h * 8 + j;
            float xv = xs[rr][d];
            float qv = cb[(long)sbi[rr] * DDIM + d];
            float diff = qv - xv;
            ov[j] = xv + diff;
            acc += (double)diff * (double)diff;
        }
        *(float4*)ob = make_float4(ov[0], ov[1], ov[2], ov[3]);
        *(float4*)(ob + 4) = make_float4(ov[4], ov[5], ov[6], ov[7]);
        sd[tid] = acc;
    }
    __syncthreads();
    for (int s = 128; s > 0; s >>= 1) {
        if (tid < s) sd[tid] += sd[tid + s];
        __syncthreads();
    }
    if (tid == 0) part[blockIdx.x] = sd[0];
}

__global__ void k_loss_final(const double* __restrict__ part, int np,
                             float* __restrict__ loss) {
    __shared__ double sd[256];
    double a = 0.0;
    for (int i = threadIdx.x; i < np; i += 256) a += part[i];
    sd[threadIdx.x] = a;
    __syncthreads();
    for (int s = 128; s > 0; s >>= 1) {
        if (threadIdx.x < s) sd[threadIdx.x] += sd[threadIdx.x + s];
        __syncthreads();
    }
    if (threadIdx.x == 0) {
        float m = (float)(sd[0] / (double)ETOT);
        loss[0] = m + 0.02f * m;
    }
}

// ---------------------------------------------------------------------------
extern "C" void kernel_launch(void* const* d_in, const int* in_sizes, int n_in,
                              void* d_out, int out_size, void* d_ws, size_t ws_size,
                              hipStream_t stream) {
    const float* inputs = (const float*)d_in[0];   // [16,128,2048] fp32
    const float* cb     = (const float*)d_in[1];   // [8192,128]    fp32
    float* outf = (float*)d_out;                   // [loss | out(B,D,T) | idx]

    char* ws = (char*)d_ws;
    _Float16* xh = (_Float16*)ws; ws += (long)NROWS * DDIM * 2;
    _Float16* eh = (_Float16*)ws; ws += (long)KCODES * DDIM * 2;
    int* cand    = (int*)ws;      ws += (long)NROWS * 16 * 4;
    double* part = (double*)ws;   ws += 2048 * 8;

    k_prep<<<dim3(3072), dim3(256), 0, stream>>>(cb, eh, inputs, xh);
    k_main<<<dim3(1024), dim3(256), 24576, stream>>>(xh, eh, cand);
    k_rf<<<dim3(2048), dim3(256), 0, stream>>>(inputs, cb, cand, outf + 1,
                                               outf + 1 + (long)ETOT, part);
    k_loss_final<<<dim3(1), dim3(256), 0, stream>>>(part, 2048, outf);
}

// Round 24
// 113.044 us; speedup vs baseline: 1.2100x; 1.0001x over previous
//
#include <hip/hip_runtime.h>
#include <hip/hip_bf16.h>

#define NROWS 32768
#define KCODES 8192
#define DDIM 128
#define TT 2048
#define ETOT 4194304  // 16*128*2048

typedef __attribute__((ext_vector_type(8))) _Float16 f16x8;
typedef __attribute__((ext_vector_type(4))) float f32x4;

// pack: (v & ~0x1FFF) | p, p in [0,8191] -> single v_and_or_b32.
__device__ __forceinline__ float pk(float v, int p) {
    return __int_as_float((__float_as_int(v) & 0xFFFFE000) | p);
}

__device__ __forceinline__ void async16(char* lds_uniform, const char* g_perlane) {
    __builtin_amdgcn_global_load_lds(
        (const __attribute__((address_space(1))) unsigned int*)g_perlane,
        (__attribute__((address_space(3))) unsigned int*)lds_uniform,
        16, 0, 0);
}

// lgkmcnt(0) REQUIRED (r22 lesson): each wave must COMPLETE its ds_reads of
// the retiring buffer before the barrier (other waves stage into it next).
#define SYNC2 asm volatile("s_waitcnt vmcnt(2) lgkmcnt(0)\n\ts_barrier" ::: "memory")
#define SYNC0 asm volatile("s_waitcnt vmcnt(0) lgkmcnt(0)\n\ts_barrier" ::: "memory")

// ---------------------------------------------------------------------------
// k_prep (merged): blocks [0,2048) = codebook normalize fp32->fp16 into MFMA
// A-fragment order (16-code tiles, 4KB); blocks [2048,3072) = transpose
// inputs [B,D,T] -> xh [N,D] fp16.
// ---------------------------------------------------------------------------
__global__ void k_prep(const float* __restrict__ cb, _Float16* __restrict__ eh,
                       const float* __restrict__ in, _Float16* __restrict__ xh) {
    __shared__ float tb[64][65];
    int bid = blockIdx.x;
    if (bid < 2048) {
        int w = (bid * blockDim.x + threadIdx.x) >> 6;  // code id
        int l = threadIdx.x & 63;
        if (w >= KCODES) return;
        const float* row = cb + (long)w * DDIM;
        float v0 = row[l], v1 = row[l + 64];
        float ss = v0 * v0 + v1 * v1;
#pragma unroll
        for (int s = 1; s < 64; s <<= 1) ss += __shfl_xor(ss, s, 64);
        float inv = 1.0f / fmaxf(sqrtf(ss), 1e-12f);
        int tile = w >> 4, c = w & 15;
#pragma unroll
        for (int e = 0; e < 2; e++) {
            int d = l + e * 64;
            float v = (e ? v1 : v0) * inv;
            int ks = d >> 5, kq = (d >> 3) & 3, dr = d & 7;
            long off = (long)tile * 2048 + ks * 512 + (kq * 16 + c) * 8 + dr;
            eh[off] = (_Float16)v;
        }
    } else {
        bid -= 2048;
        int tt0 = (bid & 31) * 64;
        int dd0 = ((bid >> 5) & 1) * 64;
        int b = bid >> 6;
        const float* base = in + (long)b * DDIM * TT;
        int tl = threadIdx.x & 63;
        int dg = threadIdx.x >> 6;
#pragma unroll
        for (int i = 0; i < 16; i++) {
            int dd = dg + i * 4;
            tb[dd][tl] = base[(long)(dd0 + dd) * TT + tt0 + tl];
        }
        __syncthreads();
        int dl = threadIdx.x & 63;
        int tg = threadIdx.x >> 6;
#pragma unroll
        for (int i = 0; i < 16; i++) {
            int t = tg + i * 4;
            long n = (long)b * TT + tt0 + t;
            xh[n * DDIM + dd0 + dl] = (_Float16)tb[dl][t];
        }
    }
}

// ---------------------------------------------------------------------------
// mfma4i: ks-outer (4 independent chains interleaved by construction).
// No setprio (r20: removal = -3.2us; priority inversion convoyed the block).
// ---------------------------------------------------------------------------
__device__ __forceinline__ void mfma4i(const char* buf, int l,
                                       const f16x8 (&bx)[4][4], f32x4 (&acc)[4]) {
    const f32x4 Z = {0.f, 0.f, 0.f, 0.f};
    f16x8 ah[4];
#pragma unroll
    for (int ks = 0; ks < 4; ks++)
        ah[ks] = *(const f16x8*)(buf + ks * 1024 + l * 16);
#pragma unroll
    for (int nf = 0; nf < 4; nf++)
        acc[nf] = __builtin_amdgcn_mfma_f32_16x16x32_f16(ah[0], bx[nf][0], Z, 0, 0, 0);
#pragma unroll
    for (int ks = 1; ks < 4; ks++)
#pragma unroll
        for (int nf = 0; nf < 4; nf++)
            acc[nf] = __builtin_amdgcn_mfma_f32_16x16x32_f16(ah[ks], bx[nf][ks], acc[nf], 0, 0, 0);
}

// {t1,t2,u1}: exact top-2 per eighth (cross-quad via t1/t2, same-quad 2nd
// via u1); feeds the rank-gated exact fp64 refine.
__device__ __forceinline__ void sel4(const f32x4 (&acc)[4], int PP,
                                     float (&t1)[4], float (&t2)[4], float (&u1)[4]) {
#pragma unroll
    for (int nf = 0; nf < 4; nf++) {
        f32x4 a = acc[nf];
        float s0 = pk(a[0], PP),     s1 = pk(a[1], PP - 1);
        float s2 = pk(a[2], PP - 2), s3 = pk(a[3], PP - 3);
        float h01 = fmaxf(s0, s1), l01 = fminf(s0, s1);
        float h23 = fmaxf(s2, s3), l23 = fminf(s2, s3);
        float m1 = fmaxf(h01, h23);                          // quad max
        float m2 = fmaxf(fminf(h01, h23), fmaxf(l01, l23));  // quad 2nd
        float n1 = fminf(t1[nf], m1); t1[nf] = fmaxf(t1[nf], m1);
        t2[nf] = fmaxf(t2[nf], n1);
        u1[nf] = fmaxf(u1[nf], m2);
    }
}

// ---------------------------------------------------------------------------
// k3 (r21 proven, 83.8us): dual-acc sel-shadow pipeline, 2-tile phases,
// 3 x 8KB buffers, counted vmcnt(2)+lgkmcnt(0), no setprio. Epilogue stores
// PACKED score floats; decode in k_rf. This is the 2-barrier K-loop family's
// plateau (~36-38% MFMA util; 7 structural variants all landed 86-108us).
// ---------------------------------------------------------------------------
__global__ __launch_bounds__(256, 3) void k_main(const _Float16* __restrict__ xh,
                                                 const _Float16* __restrict__ eh,
                                                 int* __restrict__ cand) {
    extern __shared__ char lds[];
    const int tid = threadIdx.x;
    const int l = tid & 63;
    const int w = tid >> 6;
    const int e8 = blockIdx.x & 7;
    const int rb = blockIdx.x >> 3;
    const int col = l & 15, kq = l >> 4;
    const long rbase = (long)rb * 256;

    f16x8 bx[4][4];
#pragma unroll
    for (int nf = 0; nf < 4; nf++) {
        long n = rbase + w * 64 + nf * 16 + col;
#pragma unroll
        for (int ks = 0; ks < 4; ks++)
            bx[nf][ks] = *(const f16x8*)(xh + n * DDIM + ks * 32 + kq * 8);
    }

    const float NEG = __int_as_float(0xFF800000);
    float t1[4], t2[4], u1[4];
#pragma unroll
    for (int i = 0; i < 4; i++) { t1[i] = t2[i] = u1[i] = NEG; }

    int P = 8191 - (e8 * 1024 + kq * 4);

    const char* gsrc = (const char*)eh + (long)e8 * 262144 + w * 1024 + l * 16;
    char* b0 = lds;
    char* b1 = lds + 8192;
    char* b2 = lds + 16384;

    // prologue: stage phases 0,1 (2 tiles = 2 async16 each)
    async16(b0 + w * 1024, gsrc);
    async16(b0 + 4096 + w * 1024, gsrc + 4096);
    async16(b1 + w * 1024, gsrc + 8192);
    async16(b1 + 4096 + w * 1024, gsrc + 12288);

    f32x4 accA[4], accB[4];
    int PA, PB;

    // phase 0 (peeled: no prev accB)
    SYNC2;
    async16(b2 + w * 1024, gsrc + 2 * 8192);
    async16(b2 + 4096 + w * 1024, gsrc + 2 * 8192 + 4096);
    mfma4i(b0, l, bx, accA); PA = P; P -= 16;
    mfma4i(b0 + 4096, l, bx, accB); PB = P; P -= 16;
    sel4(accA, PA, t1, t2, u1);
    { char* tp = b0; b0 = b1; b1 = b2; b2 = tp; }

    for (int p = 1; p <= 30; ++p) {
        SYNC2;
        if (p < 30) {
            async16(b2 + w * 1024, gsrc + (long)(p + 2) * 8192);
            async16(b2 + 4096 + w * 1024, gsrc + (long)(p + 2) * 8192 + 4096);
        }
        mfma4i(b0, l, bx, accA); PA = P; P -= 16;
        sel4(accB, PB, t1, t2, u1);          // prev phase's tile 1
        mfma4i(b0 + 4096, l, bx, accB); PB = P; P -= 16;
        sel4(accA, PA, t1, t2, u1);
        { char* tp = b0; b0 = b1; b1 = b2; b2 = tp; }
    }
    // phase 31 (peeled: final drain)
    SYNC0;
    mfma4i(b0, l, bx, accA); PA = P; P -= 16;
    sel4(accB, PB, t1, t2, u1);
    mfma4i(b0 + 4096, l, bx, accB); PB = P;
    sel4(accA, PA, t1, t2, u1);
    sel4(accB, PB, t1, t2, u1);

    __syncthreads();  // all staging/reads done; reuse LDS base for merge
    float* mrg = (float*)lds;  // [256 rows][13]
#pragma unroll
    for (int nf = 0; nf < 4; nf++) {
        int row = w * 64 + nf * 16 + col;
        int e = kq * 3;
        mrg[row * 13 + e + 0] = t1[nf];
        mrg[row * 13 + e + 1] = t2[nf];
        mrg[row * 13 + e + 2] = u1[nf];
    }
    __syncthreads();
    {
        float s1 = NEG, s2 = NEG;
#pragma unroll 4
        for (int e = 0; e < 12; e++) {
            float v = mrg[tid * 13 + e];
            float a1 = fminf(s1, v); s1 = fmaxf(s1, v);
            s2 = fmaxf(s2, a1);
        }
        long n = rbase + tid;
        int* cp = cand + n * 16 + e8 * 2;
        cp[0] = __float_as_int(s1);   // packed: trunc-value | (8191-code)
        cp[1] = __float_as_int(s2);
    }
}

// ---------------------------------------------------------------------------
// k4 (r21 proven, rank-gated refine + out + loss partials): block = 16 rows;
// x-slab in LDS once; 16 lanes/row rank the 16 packed candidates (16
// shuffles, values distinct) and only approx-top-4 lanes run fp64 scoring
// (cb gathers cut 4x). Winner -> idx + out + fp64 loss partial.
// ---------------------------------------------------------------------------
__global__ void k_rf(const float* __restrict__ in, const float* __restrict__ cb,
                     const int* __restrict__ cand, float* __restrict__ out,
                     float* __restrict__ idx_f, double* __restrict__ part) {
    __shared__ float xs[16][132];   // [t-local][d], pad 4
    __shared__ int sbi[16];
    __shared__ double sd[256];
    const int tid = threadIdx.x;
    const int l = tid & 63;
    const int n0 = blockIdx.x * 16;
    const int b = n0 >> 11, t0 = n0 & 2047;

    {
        int d = tid >> 1, h = tid & 1;
        const float* src = in + ((long)b * DDIM + d) * TT + t0 + h * 8;
        float4 v0 = *(const float4*)src;
        float4 v1 = *(const float4*)(src + 4);
#pragma unroll
        for (int j = 0; j < 4; j++) {
            xs[h * 8 + j][d] = ((const float*)&v0)[j];
            xs[h * 8 + 4 + j][d] = ((const float*)&v1)[j];
        }
    }
    __syncthreads();

    {
        int r = tid >> 4, k = tid & 15;
        int n = n0 + r;
        float pkv = __int_as_float(cand[n * 16 + k]);

        // rank among this row's 16 lanes (packed values are distinct)
        int rank = 0;
        int gb = l & ~15;
#pragma unroll
        for (int j = 0; j < 16; j++) {
            float o = __shfl(pkv, gb | j, 64);
            rank += (o > pkv) ? 1 : 0;
        }

        double sv = -1e300;
        int c = 0x7fffffff;
        if (rank < 4) {   // approx top-4: exact fp64 re-evaluation
            c = 8191 - (__float_as_int(pkv) & 0x1FFF);
            const float4* e = (const float4*)(cb + (long)c * DDIM);
            double dot = 0.0, nrm = 0.0;
            for (int d4 = 0; d4 < 32; d4++) {
                float4 q = e[d4];
#pragma unroll
                for (int j = 0; j < 4; j++) {
                    double xd = (double)xs[r][d4 * 4 + j];
                    double f = (double)((const float*)&q)[j];
                    dot += xd * f;
                    nrm += f * f;
                }
            }
            sv = dot / fmax(sqrt(nrm), 1e-12);
        }
#pragma unroll
        for (int s = 1; s < 16; s <<= 1) {
            double osv = __shfl_xor(sv, s, 64);
            int oc = __shfl_xor(c, s, 64);
            if (osv > sv || (osv == sv && oc < c)) { sv = osv; c = oc; }
        }
        if (k == 0) {
            sbi[r] = c;
            idx_f[n] = (float)c;
        }
    }
    __syncthreads();

    {
        int d = tid >> 1, h = tid & 1;
        float* ob = out + ((long)b * DDIM + d) * TT + t0 + h * 8;
        double acc = 0.0;
        float ov[8];
#pragma unroll
        for (int j = 0; j < 8; j++) {
            int rr = h * 8 + j;
            float xv = xs[rr][d];
            float qv = cb[(long)sbi[rr] * DDIM + d];
            float diff = qv - xv;
            ov[j] = xv + diff;
            acc += (double)diff * (double)diff;
        }
        *(float4*)ob = make_float4(ov[0], ov[1], ov[2], ov[3]);
        *(float4*)(ob + 4) = make_float4(ov[4], ov[5], ov[6], ov[7]);
        sd[tid] = acc;
    }
    __syncthreads();
    for (int s = 128; s > 0; s >>= 1) {
        if (tid < s) sd[tid] += sd[tid + s];
        __syncthreads();
    }
    if (tid == 0) part[blockIdx.x] = sd[0];
}

__global__ void k_loss_final(const double* __restrict__ part, int np,
                             float* __restrict__ loss) {
    __shared__ double sd[256];
    double a = 0.0;
    for (int i = threadIdx.x; i < np; i += 256) a += part[i];
    sd[threadIdx.x] = a;
    __syncthreads();
    for (int s = 128; s > 0; s >>= 1) {
        if (threadIdx.x < s) sd[threadIdx.x] += sd[threadIdx.x + s];
        __syncthreads();
    }
    if (threadIdx.x == 0) {
        float m = (float)(sd[0] / (double)ETOT);
        loss[0] = m + 0.02f * m;
    }
}

// ---------------------------------------------------------------------------
extern "C" void kernel_launch(void* const* d_in, const int* in_sizes, int n_in,
                              void* d_out, int out_size, void* d_ws, size_t ws_size,
                              hipStream_t stream) {
    const float* inputs = (const float*)d_in[0];   // [16,128,2048] fp32
    const float* cb     = (const float*)d_in[1];   // [8192,128]    fp32
    float* outf = (float*)d_out;                   // [loss | out(B,D,T) | idx]

    char* ws = (char*)d_ws;
    _Float16* xh = (_Float16*)ws; ws += (long)NROWS * DDIM * 2;
    _Float16* eh = (_Float16*)ws; ws += (long)KCODES * DDIM * 2;
    int* cand    = (int*)ws;      ws += (long)NROWS * 16 * 4;
    double* part = (double*)ws;   ws += 2048 * 8;

    k_prep<<<dim3(3072), dim3(256), 0, stream>>>(cb, eh, inputs, xh);
    k_main<<<dim3(1024), dim3(256), 24576, stream>>>(xh, eh, cand);
    k_rf<<<dim3(2048), dim3(256), 0, stream>>>(inputs, cb, cand, outf + 1,
                                               outf + 1 + (long)ETOT, part);
    k_loss_final<<<dim3(1), dim3(256), 0, stream>>>(part, 2048, outf);
}